// Round 1
// baseline (769.787 us; speedup 1.0000x reference)
//
#include <hip/hip_runtime.h>
#include <math.h>

#define N_NODES 4096
#define F_IN0   512
#define HEADS   4
#define O_DIM   256
#define LRELU_A 0.2f
#define MAXE    192   // max edges per row; binomial(4095,0.01) mean 41, 13+ sigma safe

// ---------------- GEMM: C[h] = A @ W[h], A [N,K] row-major, W [H,K,O], C [H,N,O]
__global__ __launch_bounds__(256) void gemm_head(const float* __restrict__ A,
                                                 const float* __restrict__ W,
                                                 float* __restrict__ C, int K) {
    const int h = blockIdx.z;
    const int rowBase = blockIdx.x * 64;
    const int colBase = blockIdx.y * 64;
    const float* Wh = W + (size_t)h * K * O_DIM;
    float* Ch = C + (size_t)h * N_NODES * O_DIM;
    __shared__ float As[16][64];
    __shared__ float Ws[16][68];
    const int tx = threadIdx.x, ty = threadIdx.y;
    const int tid = ty * 16 + tx;
    const int ar = tid >> 2;          // 0..63 (A tile row)
    const int ak = (tid & 3) * 4;     // k offset within 16
    const int wk = tid >> 4;          // 0..15 (W tile k)
    const int wc = (tid & 15) * 4;    // col offset within 64
    float acc[4][4] = {};
    for (int k0 = 0; k0 < K; k0 += 16) {
        float4 av = *(const float4*)&A[(size_t)(rowBase + ar) * K + k0 + ak];
        float4 wv = *(const float4*)&Wh[(size_t)(k0 + wk) * O_DIM + colBase + wc];
        __syncthreads();
        As[ak + 0][ar] = av.x; As[ak + 1][ar] = av.y;
        As[ak + 2][ar] = av.z; As[ak + 3][ar] = av.w;
        *(float4*)&Ws[wk][wc] = wv;
        __syncthreads();
#pragma unroll
        for (int k = 0; k < 16; ++k) {
            float a0 = As[k][ty], a1 = As[k][ty + 16], a2 = As[k][ty + 32], a3 = As[k][ty + 48];
            float b0 = Ws[k][tx], b1 = Ws[k][tx + 16], b2 = Ws[k][tx + 32], b3 = Ws[k][tx + 48];
            acc[0][0] += a0 * b0; acc[0][1] += a0 * b1; acc[0][2] += a0 * b2; acc[0][3] += a0 * b3;
            acc[1][0] += a1 * b0; acc[1][1] += a1 * b1; acc[1][2] += a1 * b2; acc[1][3] += a1 * b3;
            acc[2][0] += a2 * b0; acc[2][1] += a2 * b1; acc[2][2] += a2 * b2; acc[2][3] += a2 * b3;
            acc[3][0] += a3 * b0; acc[3][1] += a3 * b1; acc[3][2] += a3 * b2; acc[3][3] += a3 * b3;
        }
    }
#pragma unroll
    for (int i = 0; i < 4; ++i)
#pragma unroll
        for (int j = 0; j < 4; ++j)
            Ch[(size_t)(rowBase + ty + 16 * i) * O_DIM + colBase + tx + 16 * j] = acc[i][j];
}

// ---------------- scores: s_self[h,n] = h[h,n,:].a_s[h,:]; s_neigh likewise
__global__ __launch_bounds__(256) void scores_k(const float* __restrict__ hbuf,
                                                const float* __restrict__ a_s,
                                                const float* __restrict__ a_n,
                                                float* __restrict__ s_self,
                                                float* __restrict__ s_neigh) {
    const int n = blockIdx.x;
    const int head = threadIdx.x >> 6;   // wave per head
    const int lane = threadIdx.x & 63;
    const float* hp  = hbuf + ((size_t)head * N_NODES + n) * O_DIM;
    const float* asp = a_s + head * O_DIM;
    const float* anp = a_n + head * O_DIM;
    float ps = 0.f, pn = 0.f;
    for (int o = lane; o < O_DIM; o += 64) {
        float hv = hp[o];
        ps += hv * asp[o];
        pn += hv * anp[o];
    }
    for (int off = 32; off; off >>= 1) {
        ps += __shfl_down(ps, off, 64);
        pn += __shfl_down(pn, off, 64);
    }
    if (lane == 0) {
        s_self[head * N_NODES + n]  = ps;
        s_neigh[head * N_NODES + n] = pn;
    }
}

// ---------------- sparse masked softmax attention + aggregation, one block per row n
__global__ __launch_bounds__(256) void attn_k(const float* __restrict__ hbuf,
                                              const float* __restrict__ adj,
                                              const float* __restrict__ Mm,
                                              const float* __restrict__ s_self,
                                              const float* __restrict__ s_neigh,
                                              float* __restrict__ out, int layer) {
    const int n = blockIdx.x;
    const int tid = threadIdx.x;
    __shared__ int cnt;
    __shared__ int midx[MAXE];
    __shared__ float ev[MAXE][HEADS];
    __shared__ float isum[HEADS];
    if (tid == 0) cnt = 0;
    __syncthreads();
    float ss[HEADS];
#pragma unroll
    for (int h = 0; h < HEADS; ++h) ss[h] = s_self[h * N_NODES + n];
    const float* adjr = adj + (size_t)n * N_NODES;
    const float* Mr   = Mm  + (size_t)n * N_NODES;
    for (int m = tid; m < N_NODES; m += 256) {
        if (adjr[m] > 0.f) {
            float Mv = Mr[m];
            int k = atomicAdd(&cnt, 1);
            midx[k] = m;
#pragma unroll
            for (int h = 0; h < HEADS; ++h) {
                float e = (ss[h] + s_neigh[h * N_NODES + m]) * Mv;
                ev[k][h] = e > 0.f ? e : LRELU_A * e;  // leaky relu
            }
        }
    }
    __syncthreads();
    const int c = cnt;
    if (tid < HEADS) {
        float mx = -1e30f;
        for (int k = 0; k < c; ++k) mx = fmaxf(mx, ev[k][tid]);
        float s = 0.f;
        for (int k = 0; k < c; ++k) {
            float p = expf(ev[k][tid] - mx);
            ev[k][tid] = p;
            s += p;
        }
        isum[tid] = 1.f / s;
    }
    __syncthreads();
    for (int i = tid; i < c * HEADS; i += 256) {
        int k = i >> 2, h = i & 3;
        ev[k][h] *= isum[h];
    }
    __syncthreads();
    float acc[HEADS] = {0.f, 0.f, 0.f, 0.f};
    const int o = tid;  // O_DIM == blockDim
    for (int k = 0; k < c; ++k) {
        int m = midx[k];
#pragma unroll
        for (int h = 0; h < HEADS; ++h)
            acc[h] += ev[k][h] * hbuf[((size_t)h * N_NODES + m) * O_DIM + o];
    }
    if (layer == 0) {
#pragma unroll
        for (int h = 0; h < HEADS; ++h) {
            float v = acc[h];
            out[(size_t)n * (HEADS * O_DIM) + h * O_DIM + o] = v > 0.f ? v : expm1f(v);  // ELU
        }
    } else {
        out[(size_t)n * O_DIM + o] = 0.25f * (acc[0] + acc[1] + acc[2] + acc[3]);
    }
}

// ---------------- row L2 normalize in-place
__global__ __launch_bounds__(256) void norm_k(float* __restrict__ z) {
    const int n = blockIdx.x;
    const int tid = threadIdx.x;
    float v = z[(size_t)n * O_DIM + tid];
    float p = v * v;
    for (int off = 32; off; off >>= 1) p += __shfl_down(p, off, 64);
    __shared__ float wsum[4];
    if ((tid & 63) == 0) wsum[tid >> 6] = p;
    __syncthreads();
    float ssq = wsum[0] + wsum[1] + wsum[2] + wsum[3];
    float denom = fmaxf(sqrtf(ssq), 1e-12f);
    z[(size_t)n * O_DIM + tid] = v / denom;
}

// ---------------- decode: out[n,m] = sigmoid(z[n,:].z[m,:])
__global__ __launch_bounds__(256) void decode_k(const float* __restrict__ z,
                                                float* __restrict__ out) {
    const int rowBase = blockIdx.x * 64;
    const int colBase = blockIdx.y * 64;
    __shared__ float As[16][64];
    __shared__ float Bs[16][64];
    const int tx = threadIdx.x, ty = threadIdx.y;
    const int tid = ty * 16 + tx;
    const int r  = tid >> 2;
    const int kq = (tid & 3) * 4;
    float acc[4][4] = {};
    for (int k0 = 0; k0 < O_DIM; k0 += 16) {
        float4 av = *(const float4*)&z[(size_t)(rowBase + r) * O_DIM + k0 + kq];
        float4 bv = *(const float4*)&z[(size_t)(colBase + r) * O_DIM + k0 + kq];
        __syncthreads();
        As[kq + 0][r] = av.x; As[kq + 1][r] = av.y; As[kq + 2][r] = av.z; As[kq + 3][r] = av.w;
        Bs[kq + 0][r] = bv.x; Bs[kq + 1][r] = bv.y; Bs[kq + 2][r] = bv.z; Bs[kq + 3][r] = bv.w;
        __syncthreads();
#pragma unroll
        for (int k = 0; k < 16; ++k) {
            float a0 = As[k][ty], a1 = As[k][ty + 16], a2 = As[k][ty + 32], a3 = As[k][ty + 48];
            float b0 = Bs[k][tx], b1 = Bs[k][tx + 16], b2 = Bs[k][tx + 32], b3 = Bs[k][tx + 48];
            acc[0][0] += a0 * b0; acc[0][1] += a0 * b1; acc[0][2] += a0 * b2; acc[0][3] += a0 * b3;
            acc[1][0] += a1 * b0; acc[1][1] += a1 * b1; acc[1][2] += a1 * b2; acc[1][3] += a1 * b3;
            acc[2][0] += a2 * b0; acc[2][1] += a2 * b1; acc[2][2] += a2 * b2; acc[2][3] += a2 * b3;
            acc[3][0] += a3 * b0; acc[3][1] += a3 * b1; acc[3][2] += a3 * b2; acc[3][3] += a3 * b3;
        }
    }
#pragma unroll
    for (int i = 0; i < 4; ++i)
#pragma unroll
        for (int j = 0; j < 4; ++j) {
            float v = acc[i][j];
            out[(size_t)(rowBase + ty + 16 * i) * N_NODES + colBase + tx + 16 * j] =
                1.f / (1.f + expf(-v));
        }
}

extern "C" void kernel_launch(void* const* d_in, const int* in_sizes, int n_in,
                              void* d_out, int out_size, void* d_ws, size_t ws_size,
                              hipStream_t stream) {
    const float* x   = (const float*)d_in[0];
    const float* adj = (const float*)d_in[1];
    const float* Mm  = (const float*)d_in[2];
    const float* W0  = (const float*)d_in[3];
    const float* as0 = (const float*)d_in[4];
    const float* an0 = (const float*)d_in[5];
    const float* W1  = (const float*)d_in[6];
    const float* as1 = (const float*)d_in[7];
    const float* an1 = (const float*)d_in[8];
    float* out = (float*)d_out;
    float* ws  = (float*)d_ws;

    float* hbuf    = ws;                      // [H,N,O] 4,194,304 f32 (h0, later h1)
    float* hin1    = hbuf + 4194304;          // [N,H*O] 4,194,304 f32
    float* s_self  = hin1 + 4194304;          // [H,N]
    float* s_neigh = s_self + HEADS * N_NODES;
    float* zbuf    = out + (size_t)N_NODES * N_NODES;  // z lives in d_out tail

    dim3 bt(16, 16);
    // layer 0
    gemm_head<<<dim3(N_NODES / 64, O_DIM / 64, HEADS), bt, 0, stream>>>(x, W0, hbuf, F_IN0);
    scores_k<<<N_NODES, 256, 0, stream>>>(hbuf, as0, an0, s_self, s_neigh);
    attn_k<<<N_NODES, 256, 0, stream>>>(hbuf, adj, Mm, s_self, s_neigh, hin1, 0);
    // layer 1
    gemm_head<<<dim3(N_NODES / 64, O_DIM / 64, HEADS), bt, 0, stream>>>(hin1, W1, hbuf, HEADS * O_DIM);
    scores_k<<<N_NODES, 256, 0, stream>>>(hbuf, as1, an1, s_self, s_neigh);
    attn_k<<<N_NODES, 256, 0, stream>>>(hbuf, adj, Mm, s_self, s_neigh, zbuf, 1);
    // normalize + decode
    norm_k<<<N_NODES, 256, 0, stream>>>(zbuf);
    decode_k<<<dim3(N_NODES / 64, N_NODES / 64), bt, 0, stream>>>(zbuf, out);
}

// Round 2
// 460.723 us; speedup vs baseline: 1.6708x; 1.6708x over previous
//
#include <hip/hip_runtime.h>
#include <hip/hip_bf16.h>
#include <math.h>

#define N_NODES 4096
#define F_IN0   512
#define HEADS   4
#define O_DIM   256
#define LRELU_A 0.2f
#define MAXE    192

typedef __bf16 bf16_t;
typedef bf16_t bf16x8 __attribute__((ext_vector_type(8)));
typedef float f32x4 __attribute__((ext_vector_type(4)));

__device__ __forceinline__ unsigned short f2b(float f) {
    __hip_bfloat16 t = __float2bfloat16(f);
    return __builtin_bit_cast(unsigned short, t);
}

#define GLOAD_LDS(g, l) \
    __builtin_amdgcn_global_load_lds((const __attribute__((address_space(1))) unsigned int*)(g), \
                                     (__attribute__((address_space(3))) unsigned int*)(l), 16, 0, 0)

// ---------------- fp32 -> bf16 bulk convert (n4 = count of float4 groups)
__global__ __launch_bounds__(256) void f2bf_k(const float* __restrict__ src,
                                              unsigned short* __restrict__ dst, int n4) {
    int i = blockIdx.x * blockDim.x + threadIdx.x;
    if (i < n4) {
        float4 v = ((const float4*)src)[i];
        ushort4 o;
        o.x = f2b(v.x); o.y = f2b(v.y); o.z = f2b(v.z); o.w = f2b(v.w);
        ((ushort4*)dst)[i] = o;
    }
}

// ---------------- W [H,K,O] fp32  ->  Wt [H,O,K] bf16
__global__ __launch_bounds__(256) void transpose_bf16(const float* __restrict__ W,
                                                      unsigned short* __restrict__ Wt,
                                                      int K, int O) {
    __shared__ float t[32][33];
    const float* Wh = W + (size_t)blockIdx.z * K * O;
    unsigned short* Wth = Wt + (size_t)blockIdx.z * K * O;
    const int k0 = blockIdx.x * 32, o0 = blockIdx.y * 32;
    const int tx = threadIdx.x, ty = threadIdx.y;  // 32 x 8
    for (int r = ty; r < 32; r += 8) t[r][tx] = Wh[(size_t)(k0 + r) * O + o0 + tx];
    __syncthreads();
    for (int r = ty; r < 32; r += 8)
        Wth[(size_t)(o0 + r) * K + k0 + tx] = f2b(t[tx][r]);
}

// ---------------- MFMA NT GEMM: C[m,n] = sum_k A[m,k]*B[n,k]
// A: bf16 [M,K] rows, B: bf16 [N,K] rows, C: fp32, ldc given.
// grid (M/128, N/128, nz); B += z*bStride, C += z*cStride.
// EPI: 0 plain store, 1 sigmoid.
template <int EPI>
__global__ __launch_bounds__(256) void mfma_nt(const bf16_t* __restrict__ A,
                                               const bf16_t* __restrict__ B,
                                               float* __restrict__ C,
                                               int K, int ldc,
                                               unsigned long long bStride,
                                               unsigned long long cStride) {
    B += blockIdx.z * bStride;
    C += blockIdx.z * cStride;
    __shared__ bf16_t sA[128 * 32];
    __shared__ bf16_t sB[128 * 32];
    const int tid  = threadIdx.x;
    const int lane = tid & 63;
    const int wave = tid >> 6;
    const int wr = (wave >> 1) * 64;
    const int wc = (wave & 1) * 64;
    const int rowBase = blockIdx.x * 128;
    const int colBase = blockIdx.y * 128;
    const int l15  = lane & 15;
    const int quad = lane >> 4;

    const int sm = tid & 127;   // staging: tile row
    const int sc = tid >> 7;    // staging: k-chunk 0..1 (and +2 on 2nd call)
    const bf16_t* aRow = A + (size_t)(rowBase + sm) * K + sc * 8;
    const bf16_t* bRow = B + (size_t)(colBase + sm) * K + sc * 8;
    bf16_t* sA0 = &sA[(tid & ~63) * 8];
    bf16_t* sA1 = &sA[(256 + (tid & ~63)) * 8];
    bf16_t* sB0 = &sB[(tid & ~63) * 8];
    bf16_t* sB1 = &sB[(256 + (tid & ~63)) * 8];

    f32x4 acc[4][4] = {};

    for (int k0 = 0; k0 < K; k0 += 32) {
        GLOAD_LDS(aRow + k0,      sA0);
        GLOAD_LDS(aRow + k0 + 16, sA1);
        GLOAD_LDS(bRow + k0,      sB0);
        GLOAD_LDS(bRow + k0 + 16, sB1);
        __syncthreads();
        bf16x8 af[4], bf[4];
#pragma unroll
        for (int i = 0; i < 4; ++i) {
            af[i] = *(bf16x8*)&sA[(quad * 128 + wr + i * 16 + l15) * 8];
            bf[i] = *(bf16x8*)&sB[(quad * 128 + wc + i * 16 + l15) * 8];
        }
#pragma unroll
        for (int i = 0; i < 4; ++i)
#pragma unroll
            for (int j = 0; j < 4; ++j)
                acc[i][j] = __builtin_amdgcn_mfma_f32_16x16x32_bf16(af[i], bf[j], acc[i][j], 0, 0, 0);
        __syncthreads();
    }

    const int orow = rowBase + wr + quad * 4;
    const int ocol = colBase + wc + l15;
#pragma unroll
    for (int i = 0; i < 4; ++i)
#pragma unroll
        for (int j = 0; j < 4; ++j)
#pragma unroll
            for (int r = 0; r < 4; ++r) {
                float v = acc[i][j][r];
                if (EPI == 1) v = 1.f / (1.f + expf(-v));
                C[(size_t)(orow + i * 16 + r) * ldc + ocol + j * 16] = v;
            }
}

// ---------------- scores: s_self[h,n] = h[h,n,:].a_s[h,:]; s_neigh likewise
__global__ __launch_bounds__(256) void scores_k(const float* __restrict__ hbuf,
                                                const float* __restrict__ a_s,
                                                const float* __restrict__ a_n,
                                                float* __restrict__ s_self,
                                                float* __restrict__ s_neigh) {
    const int n = blockIdx.x;
    const int head = threadIdx.x >> 6;
    const int lane = threadIdx.x & 63;
    const float* hp  = hbuf + ((size_t)head * N_NODES + n) * O_DIM;
    const float* asp = a_s + head * O_DIM;
    const float* anp = a_n + head * O_DIM;
    float ps = 0.f, pn = 0.f;
    for (int o = lane; o < O_DIM; o += 64) {
        float hv = hp[o];
        ps += hv * asp[o];
        pn += hv * anp[o];
    }
    for (int off = 32; off; off >>= 1) {
        ps += __shfl_down(ps, off, 64);
        pn += __shfl_down(pn, off, 64);
    }
    if (lane == 0) {
        s_self[head * N_NODES + n]  = ps;
        s_neigh[head * N_NODES + n] = pn;
    }
}

// ---------------- sparse masked softmax attention + aggregation, one block per row n
__global__ __launch_bounds__(256) void attn_k(const float* __restrict__ hbuf,
                                              const float* __restrict__ adj,
                                              const float* __restrict__ Mm,
                                              const float* __restrict__ s_self,
                                              const float* __restrict__ s_neigh,
                                              unsigned short* __restrict__ out0,
                                              float* __restrict__ out1, int layer) {
    const int n = blockIdx.x;
    const int tid = threadIdx.x;
    __shared__ int cnt;
    __shared__ int midx[MAXE];
    __shared__ float ev[MAXE][HEADS];
    __shared__ float isum[HEADS];
    if (tid == 0) cnt = 0;
    __syncthreads();
    float ss[HEADS];
#pragma unroll
    for (int h = 0; h < HEADS; ++h) ss[h] = s_self[h * N_NODES + n];
    const float* adjr = adj + (size_t)n * N_NODES;
    const float* Mr   = Mm  + (size_t)n * N_NODES;
    for (int m0 = tid * 4; m0 < N_NODES; m0 += 1024) {
        const float4 a4 = *(const float4*)&adjr[m0];
        const float av[4] = {a4.x, a4.y, a4.z, a4.w};
#pragma unroll
        for (int q = 0; q < 4; ++q) {
            if (av[q] > 0.f) {
                int m = m0 + q;
                float Mv = Mr[m];  // only fetch M at edges
                int k = atomicAdd(&cnt, 1);
                midx[k] = m;
#pragma unroll
                for (int h = 0; h < HEADS; ++h) {
                    float e = (ss[h] + s_neigh[h * N_NODES + m]) * Mv;
                    ev[k][h] = e > 0.f ? e : LRELU_A * e;
                }
            }
        }
    }
    __syncthreads();
    const int c = cnt;
    if (tid < HEADS) {
        float mx = -1e30f;
        for (int k = 0; k < c; ++k) mx = fmaxf(mx, ev[k][tid]);
        float s = 0.f;
        for (int k = 0; k < c; ++k) {
            float p = expf(ev[k][tid] - mx);
            ev[k][tid] = p;
            s += p;
        }
        isum[tid] = 1.f / s;
    }
    __syncthreads();
    for (int i = tid; i < c * HEADS; i += 256) {
        int k = i >> 2, h = i & 3;
        ev[k][h] *= isum[h];
    }
    __syncthreads();
    float acc[HEADS] = {0.f, 0.f, 0.f, 0.f};
    const int o = tid;
    for (int k = 0; k < c; ++k) {
        int m = midx[k];
#pragma unroll
        for (int h = 0; h < HEADS; ++h)
            acc[h] += ev[k][h] * hbuf[((size_t)h * N_NODES + m) * O_DIM + o];
    }
    if (layer == 0) {
#pragma unroll
        for (int h = 0; h < HEADS; ++h) {
            float v = acc[h];
            v = v > 0.f ? v : expm1f(v);  // ELU
            out0[(size_t)n * (HEADS * O_DIM) + h * O_DIM + o] = f2b(v);
        }
    } else {
        out1[(size_t)n * O_DIM + o] = 0.25f * (acc[0] + acc[1] + acc[2] + acc[3]);
    }
}

// ---------------- row L2 normalize in-place (fp32) + bf16 copy
__global__ __launch_bounds__(256) void norm_k(float* __restrict__ z,
                                              unsigned short* __restrict__ zb) {
    const int n = blockIdx.x;
    const int tid = threadIdx.x;
    float v = z[(size_t)n * O_DIM + tid];
    float p = v * v;
    for (int off = 32; off; off >>= 1) p += __shfl_down(p, off, 64);
    __shared__ float wsum[4];
    if ((tid & 63) == 0) wsum[tid >> 6] = p;
    __syncthreads();
    float ssq = wsum[0] + wsum[1] + wsum[2] + wsum[3];
    float denom = fmaxf(sqrtf(ssq), 1e-12f);
    float zn = v / denom;
    z[(size_t)n * O_DIM + tid] = zn;
    zb[(size_t)n * O_DIM + tid] = f2b(zn);
}

extern "C" void kernel_launch(void* const* d_in, const int* in_sizes, int n_in,
                              void* d_out, int out_size, void* d_ws, size_t ws_size,
                              hipStream_t stream) {
    const float* x   = (const float*)d_in[0];
    const float* adj = (const float*)d_in[1];
    const float* Mm  = (const float*)d_in[2];
    const float* W0  = (const float*)d_in[3];
    const float* as0 = (const float*)d_in[4];
    const float* an0 = (const float*)d_in[5];
    const float* W1  = (const float*)d_in[6];
    const float* as1 = (const float*)d_in[7];
    const float* an1 = (const float*)d_in[8];
    float* out = (float*)d_out;
    float* ws  = (float*)d_ws;

    // ws layout (33.1 MB total)
    float* hbuf = ws;                                              // [H,N,O] fp32, 16 MB
    unsigned short* hin1b = (unsigned short*)(hbuf + 4194304);     // [N,H*O] bf16, 8 MB
    unsigned short* xb    = hin1b + 4194304;                       // [N,F] bf16, 4 MB
    unsigned short* wt0   = xb + 2097152;                          // [H,O,512] bf16, 1 MB
    unsigned short* wt1   = wt0 + 524288;                          // [H,O,1024] bf16, 2 MB
    unsigned short* zb    = wt1 + 1048576;                         // [N,O] bf16, 2 MB
    float* s_self  = (float*)(zb + 1048576);                       // [H,N]
    float* s_neigh = s_self + HEADS * N_NODES;
    float* zbuf = out + (size_t)N_NODES * N_NODES;                 // z fp32 lives in d_out tail

    // precompute bf16 operands
    f2bf_k<<<2048, 256, 0, stream>>>(x, xb, 524288);
    transpose_bf16<<<dim3(16, 8, 4), dim3(32, 8), 0, stream>>>(W0, wt0, F_IN0, O_DIM);
    transpose_bf16<<<dim3(32, 8, 4), dim3(32, 8), 0, stream>>>(W1, wt1, HEADS * O_DIM, O_DIM);

    // layer 0: h0[h] = x @ W0[h]
    mfma_nt<0><<<dim3(32, 2, 4), 256, 0, stream>>>((const bf16_t*)xb, (const bf16_t*)wt0, hbuf,
                                                   F_IN0, O_DIM,
                                                   (unsigned long long)O_DIM * F_IN0,
                                                   (unsigned long long)N_NODES * O_DIM);
    scores_k<<<N_NODES, 256, 0, stream>>>(hbuf, as0, an0, s_self, s_neigh);
    attn_k<<<N_NODES, 256, 0, stream>>>(hbuf, adj, Mm, s_self, s_neigh, hin1b, nullptr, 0);

    // layer 1: h1[h] = hin1 @ W1[h]
    mfma_nt<0><<<dim3(32, 2, 4), 256, 0, stream>>>((const bf16_t*)hin1b, (const bf16_t*)wt1, hbuf,
                                                   HEADS * O_DIM, O_DIM,
                                                   (unsigned long long)O_DIM * HEADS * O_DIM,
                                                   (unsigned long long)N_NODES * O_DIM);
    scores_k<<<N_NODES, 256, 0, stream>>>(hbuf, as1, an1, s_self, s_neigh);
    attn_k<<<N_NODES, 256, 0, stream>>>(hbuf, adj, Mm, s_self, s_neigh, nullptr, zbuf, 1);

    // normalize + decode
    norm_k<<<N_NODES, 256, 0, stream>>>(zbuf, zb);
    mfma_nt<1><<<dim3(32, 32, 1), 256, 0, stream>>>((const bf16_t*)zb, (const bf16_t*)zb, out,
                                                    O_DIM, N_NODES, 0ULL, 0ULL);
}

// Round 3
// 364.014 us; speedup vs baseline: 2.1147x; 1.2657x over previous
//
#include <hip/hip_runtime.h>
#include <hip/hip_bf16.h>
#include <math.h>

#define N_NODES 4096
#define F_IN0   512
#define HEADS   4
#define O_DIM   256
#define HO      1024   // HEADS*O_DIM
#define LRELU_A 0.2f
#define MAXE    192

typedef __bf16 bf16_t;
typedef bf16_t bf16x8 __attribute__((ext_vector_type(8)));
typedef float f32x4 __attribute__((ext_vector_type(4)));

__device__ __forceinline__ unsigned short f2b(float f) {
    __hip_bfloat16 t = __float2bfloat16(f);
    return __builtin_bit_cast(unsigned short, t);
}
__device__ __forceinline__ float b2f(unsigned short u) {
    unsigned int v = ((unsigned int)u) << 16;
    return __builtin_bit_cast(float, v);
}

#define GLOAD_LDS(g, l) \
    __builtin_amdgcn_global_load_lds((const __attribute__((address_space(1))) unsigned int*)(g), \
                                     (__attribute__((address_space(3))) unsigned int*)(l), 16, 0, 0)

// ---------------- fp32 -> bf16 bulk convert
__global__ __launch_bounds__(256) void f2bf_k(const float* __restrict__ src,
                                              unsigned short* __restrict__ dst, int n4) {
    int i = blockIdx.x * blockDim.x + threadIdx.x;
    if (i < n4) {
        float4 v = ((const float4*)src)[i];
        ushort4 o;
        o.x = f2b(v.x); o.y = f2b(v.y); o.z = f2b(v.z); o.w = f2b(v.w);
        ((ushort4*)dst)[i] = o;
    }
}

// ---------------- W [H,K,O] fp32 -> Wt [H,O,K] bf16
__global__ __launch_bounds__(256) void transpose_bf16(const float* __restrict__ W,
                                                      unsigned short* __restrict__ Wt,
                                                      int K, int O) {
    __shared__ float t[32][33];
    const float* Wh = W + (size_t)blockIdx.z * K * O;
    unsigned short* Wth = Wt + (size_t)blockIdx.z * K * O;
    const int k0 = blockIdx.x * 32, o0 = blockIdx.y * 32;
    const int tx = threadIdx.x, ty = threadIdx.y;  // 32 x 8
    for (int r = ty; r < 32; r += 8) t[r][tx] = Wh[(size_t)(k0 + r) * O + o0 + tx];
    __syncthreads();
    for (int r = ty; r < 32; r += 8)
        Wth[(size_t)(o0 + r) * K + k0 + tx] = f2b(t[tx][r]);
}

// ---------------- edge list build: one adj scan, compact CSR-ish [n][MAXE]
__global__ __launch_bounds__(256) void edges_k(const float* __restrict__ adj,
                                               const float* __restrict__ Mm,
                                               int* __restrict__ ecnt,
                                               int* __restrict__ eidx,
                                               float* __restrict__ eMv) {
    const int n = blockIdx.x;
    const int tid = threadIdx.x;
    __shared__ int cnt;
    if (tid == 0) cnt = 0;
    __syncthreads();
    const float* adjr = adj + (size_t)n * N_NODES;
    const float* Mr   = Mm  + (size_t)n * N_NODES;
    for (int m0 = tid * 4; m0 < N_NODES; m0 += 1024) {
        const float4 a4 = *(const float4*)&adjr[m0];
        const float av[4] = {a4.x, a4.y, a4.z, a4.w};
#pragma unroll
        for (int q = 0; q < 4; ++q) {
            if (av[q] > 0.f) {
                int m = m0 + q;
                int k = atomicAdd(&cnt, 1);
                eidx[(size_t)n * MAXE + k] = m;
                eMv[(size_t)n * MAXE + k]  = Mr[m];
            }
        }
    }
    __syncthreads();
    if (tid == 0) ecnt[n] = cnt;
}

// ---------------- MFMA NT GEMM: C[m,n] = sum_k A[m,k]*B[n,k]
// EPI: 0 fp32 store, 1 sigmoid fp32 store, 2 bf16 store.
template <int EPI>
__global__ __launch_bounds__(256) void mfma_nt(const bf16_t* __restrict__ A,
                                               const bf16_t* __restrict__ B,
                                               void* __restrict__ Cv,
                                               int K, int ldc,
                                               unsigned long long bStride,
                                               unsigned long long cStride) {
    B += blockIdx.z * bStride;
    const size_t zoff = (size_t)blockIdx.z * cStride;
    __shared__ bf16_t sA[128 * 32];
    __shared__ bf16_t sB[128 * 32];
    const int tid  = threadIdx.x;
    const int lane = tid & 63;
    const int wave = tid >> 6;
    const int wr = (wave >> 1) * 64;
    const int wc = (wave & 1) * 64;
    const int rowBase = blockIdx.x * 128;
    const int colBase = blockIdx.y * 128;
    const int l15  = lane & 15;
    const int quad = lane >> 4;

    const int sm = tid & 127;
    const int sc = tid >> 7;
    const bf16_t* aRow = A + (size_t)(rowBase + sm) * K + sc * 8;
    const bf16_t* bRow = B + (size_t)(colBase + sm) * K + sc * 8;
    bf16_t* sA0 = &sA[(tid & ~63) * 8];
    bf16_t* sA1 = &sA[(256 + (tid & ~63)) * 8];
    bf16_t* sB0 = &sB[(tid & ~63) * 8];
    bf16_t* sB1 = &sB[(256 + (tid & ~63)) * 8];

    f32x4 acc[4][4] = {};

    for (int k0 = 0; k0 < K; k0 += 32) {
        GLOAD_LDS(aRow + k0,      sA0);
        GLOAD_LDS(aRow + k0 + 16, sA1);
        GLOAD_LDS(bRow + k0,      sB0);
        GLOAD_LDS(bRow + k0 + 16, sB1);
        __syncthreads();
        bf16x8 af[4], bf[4];
#pragma unroll
        for (int i = 0; i < 4; ++i) {
            af[i] = *(bf16x8*)&sA[(quad * 128 + wr + i * 16 + l15) * 8];
            bf[i] = *(bf16x8*)&sB[(quad * 128 + wc + i * 16 + l15) * 8];
        }
#pragma unroll
        for (int i = 0; i < 4; ++i)
#pragma unroll
            for (int j = 0; j < 4; ++j)
                acc[i][j] = __builtin_amdgcn_mfma_f32_16x16x32_bf16(af[i], bf[j], acc[i][j], 0, 0, 0);
        __syncthreads();
    }

    const int orow = rowBase + wr + quad * 4;
    const int ocol = colBase + wc + l15;
#pragma unroll
    for (int i = 0; i < 4; ++i)
#pragma unroll
        for (int j = 0; j < 4; ++j)
#pragma unroll
            for (int r = 0; r < 4; ++r) {
                float v = acc[i][j][r];
                size_t idx = zoff + (size_t)(orow + i * 16 + r) * ldc + ocol + j * 16;
                if (EPI == 2) {
                    ((unsigned short*)Cv)[idx] = f2b(v);
                } else {
                    if (EPI == 1) v = 1.f / (1.f + expf(-v));
                    ((float*)Cv)[idx] = v;
                }
            }
}

// ---------------- scores from bf16 h[n][h*256+o]: s4[n][h] interleaved
__global__ __launch_bounds__(256) void scores_k(const unsigned short* __restrict__ hb,
                                                const float* __restrict__ a_s,
                                                const float* __restrict__ a_n,
                                                float* __restrict__ s_self4,
                                                float* __restrict__ s_neigh4) {
    const int n = blockIdx.x;
    const int head = threadIdx.x >> 6;
    const int lane = threadIdx.x & 63;
    const ushort4 hv = *(const ushort4*)&hb[(size_t)n * HO + head * O_DIM + lane * 4];
    const float4 av = *(const float4*)&a_s[head * O_DIM + lane * 4];
    const float4 nv = *(const float4*)&a_n[head * O_DIM + lane * 4];
    float h0 = b2f(hv.x), h1 = b2f(hv.y), h2 = b2f(hv.z), h3 = b2f(hv.w);
    float ps = h0 * av.x + h1 * av.y + h2 * av.z + h3 * av.w;
    float pn = h0 * nv.x + h1 * nv.y + h2 * nv.z + h3 * nv.w;
    for (int off = 32; off; off >>= 1) {
        ps += __shfl_down(ps, off, 64);
        pn += __shfl_down(pn, off, 64);
    }
    if (lane == 0) {
        s_self4[n * HEADS + head]  = ps;
        s_neigh4[n * HEADS + head] = pn;
    }
}

// ---------------- sparse attention from edge list; h bf16 n-major
__global__ __launch_bounds__(256) void attn_k(const unsigned short* __restrict__ hb,
                                              const int* __restrict__ ecnt,
                                              const int* __restrict__ eidx,
                                              const float* __restrict__ eMv,
                                              const float* __restrict__ s_self4,
                                              const float* __restrict__ s_neigh4,
                                              unsigned short* __restrict__ out0,
                                              float* __restrict__ out1, int layer) {
    const int n = blockIdx.x;
    const int tid = threadIdx.x;
    __shared__ int midx[MAXE];
    __shared__ float ev[MAXE][HEADS];
    __shared__ float isum[HEADS];
    __shared__ float red[HO];
    const int c = ecnt[n];
    if (tid < c) {
        const int m = eidx[(size_t)n * MAXE + tid];
        const float Mv = eMv[(size_t)n * MAXE + tid];
        midx[tid] = m;
        const float4 ss = *(const float4*)&s_self4[n * HEADS];
        const float4 sn = *(const float4*)&s_neigh4[m * HEADS];
        float e0 = (ss.x + sn.x) * Mv, e1 = (ss.y + sn.y) * Mv;
        float e2 = (ss.z + sn.z) * Mv, e3 = (ss.w + sn.w) * Mv;
        ev[tid][0] = e0 > 0.f ? e0 : LRELU_A * e0;
        ev[tid][1] = e1 > 0.f ? e1 : LRELU_A * e1;
        ev[tid][2] = e2 > 0.f ? e2 : LRELU_A * e2;
        ev[tid][3] = e3 > 0.f ? e3 : LRELU_A * e3;
    }
    __syncthreads();
    if (tid < HEADS) {
        float mx = -1e30f;
        for (int k = 0; k < c; ++k) mx = fmaxf(mx, ev[k][tid]);
        float s = 0.f;
        for (int k = 0; k < c; ++k) {
            float p = expf(ev[k][tid] - mx);
            ev[k][tid] = p;
            s += p;
        }
        isum[tid] = 1.f / s;
    }
    __syncthreads();
    for (int i = tid; i < c * HEADS; i += 256) {
        int k = i >> 2, h = i & 3;
        ev[k][h] *= isum[h];
    }
    __syncthreads();
    // aggregation: thread t covers elements [t*4, t*4+3] of the 1024-wide row
    const int head = tid >> 6;
    float a0 = 0.f, a1 = 0.f, a2 = 0.f, a3 = 0.f;
    for (int k = 0; k < c; ++k) {
        const int m = midx[k];
        const float w = ev[k][head];
        const ushort4 hv = *(const ushort4*)&hb[(size_t)m * HO + tid * 4];
        a0 += w * b2f(hv.x); a1 += w * b2f(hv.y);
        a2 += w * b2f(hv.z); a3 += w * b2f(hv.w);
    }
    if (layer == 0) {
        a0 = a0 > 0.f ? a0 : expm1f(a0);
        a1 = a1 > 0.f ? a1 : expm1f(a1);
        a2 = a2 > 0.f ? a2 : expm1f(a2);
        a3 = a3 > 0.f ? a3 : expm1f(a3);
        ushort4 o;
        o.x = f2b(a0); o.y = f2b(a1); o.z = f2b(a2); o.w = f2b(a3);
        *(ushort4*)&out0[(size_t)n * HO + tid * 4] = o;
    } else {
        red[tid * 4 + 0] = a0; red[tid * 4 + 1] = a1;
        red[tid * 4 + 2] = a2; red[tid * 4 + 3] = a3;
        __syncthreads();
        const int o = tid;  // 256 threads = O_DIM
        out1[(size_t)n * O_DIM + o] =
            0.25f * (red[o] + red[O_DIM + o] + red[2 * O_DIM + o] + red[3 * O_DIM + o]);
    }
}

// ---------------- row L2 normalize + bf16 copy
__global__ __launch_bounds__(256) void norm_k(float* __restrict__ z,
                                              unsigned short* __restrict__ zb) {
    const int n = blockIdx.x;
    const int tid = threadIdx.x;
    float v = z[(size_t)n * O_DIM + tid];
    float p = v * v;
    for (int off = 32; off; off >>= 1) p += __shfl_down(p, off, 64);
    __shared__ float wsum[4];
    if ((tid & 63) == 0) wsum[tid >> 6] = p;
    __syncthreads();
    float ssq = wsum[0] + wsum[1] + wsum[2] + wsum[3];
    float denom = fmaxf(sqrtf(ssq), 1e-12f);
    float zn = v / denom;
    z[(size_t)n * O_DIM + tid] = zn;
    zb[(size_t)n * O_DIM + tid] = f2b(zn);
}

extern "C" void kernel_launch(void* const* d_in, const int* in_sizes, int n_in,
                              void* d_out, int out_size, void* d_ws, size_t ws_size,
                              hipStream_t stream) {
    const float* x   = (const float*)d_in[0];
    const float* adj = (const float*)d_in[1];
    const float* Mm  = (const float*)d_in[2];
    const float* W0  = (const float*)d_in[3];
    const float* as0 = (const float*)d_in[4];
    const float* an0 = (const float*)d_in[5];
    const float* W1  = (const float*)d_in[6];
    const float* as1 = (const float*)d_in[7];
    const float* an1 = (const float*)d_in[8];
    float* out = (float*)d_out;

    // ws layout (~31.2 MB)
    unsigned short* hb    = (unsigned short*)d_ws;        // [N][HO] bf16, 8 MB
    unsigned short* hin1b = hb + (size_t)N_NODES * HO;    // [N][HO] bf16, 8 MB
    unsigned short* xb    = hin1b + (size_t)N_NODES * HO; // [N][F] bf16, 4 MB
    unsigned short* wt0   = xb + (size_t)N_NODES * F_IN0; // 1 MB
    unsigned short* wt1   = wt0 + HEADS * O_DIM * F_IN0;  // 2 MB
    unsigned short* zb    = wt1 + HEADS * O_DIM * HO;     // [N][O] bf16, 2 MB
    float* s_self4  = (float*)(zb + (size_t)N_NODES * O_DIM);  // [N][4]
    float* s_neigh4 = s_self4 + N_NODES * HEADS;               // [N][4]
    int*   eidx = (int*)(s_neigh4 + N_NODES * HEADS);          // [N][MAXE] 3 MB
    float* eMv  = (float*)(eidx + (size_t)N_NODES * MAXE);     // 3 MB
    int*   ecnt = (int*)(eMv + (size_t)N_NODES * MAXE);        // 16 KB
    float* zbuf = out + (size_t)N_NODES * N_NODES;             // z fp32 in d_out tail

    // precompute
    f2bf_k<<<2048, 256, 0, stream>>>(x, xb, 524288);
    transpose_bf16<<<dim3(16, 8, 4), dim3(32, 8), 0, stream>>>(W0, wt0, F_IN0, O_DIM);
    transpose_bf16<<<dim3(32, 8, 4), dim3(32, 8), 0, stream>>>(W1, wt1, HO, O_DIM);
    edges_k<<<N_NODES, 256, 0, stream>>>(adj, Mm, ecnt, eidx, eMv);

    // layer 0: h[n][h*256+o] = x @ W0[h]  (ldc=HO, per-head col offset = h*256)
    mfma_nt<2><<<dim3(32, 2, 4), 256, 0, stream>>>((const bf16_t*)xb, (const bf16_t*)wt0, hb,
                                                   F_IN0, HO,
                                                   (unsigned long long)O_DIM * F_IN0,
                                                   (unsigned long long)O_DIM);
    scores_k<<<N_NODES, 256, 0, stream>>>(hb, as0, an0, s_self4, s_neigh4);
    attn_k<<<N_NODES, 256, 0, stream>>>(hb, ecnt, eidx, eMv, s_self4, s_neigh4, hin1b, nullptr, 0);

    // layer 1
    mfma_nt<2><<<dim3(32, 2, 4), 256, 0, stream>>>((const bf16_t*)hin1b, (const bf16_t*)wt1, hb,
                                                   HO, HO,
                                                   (unsigned long long)O_DIM * HO,
                                                   (unsigned long long)O_DIM);
    scores_k<<<N_NODES, 256, 0, stream>>>(hb, as1, an1, s_self4, s_neigh4);
    attn_k<<<N_NODES, 256, 0, stream>>>(hb, ecnt, eidx, eMv, s_self4, s_neigh4, nullptr, zbuf, 1);

    // normalize + decode
    norm_k<<<N_NODES, 256, 0, stream>>>(zbuf, zb);
    mfma_nt<1><<<dim3(32, 32, 1), 256, 0, stream>>>((const bf16_t*)zb, (const bf16_t*)zb, out,
                                                    O_DIM, N_NODES, 0ULL, 0ULL);
}